// Round 2
// baseline (805.331 us; speedup 1.0000x reference)
//
#include <hip/hip_runtime.h>
#include <hip/hip_bf16.h>

#define HW 16384   // 128*128
#define W_ 128
#define H_ 128

// ---------------------------------------------------------------------------
// pack: dst[0..96) = X1[0], dst[96..192) = X2[0]   (channel concat, batch 0)
// ---------------------------------------------------------------------------
__global__ void pack_concat(const float* __restrict__ X1,
                            const float* __restrict__ X2,
                            float* __restrict__ dst) {
    int i = blockIdx.x * 256 + threadIdx.x;       // float4 index
    const int n1 = 96 * HW / 4;                   // 393216
    float4* d4 = (float4*)dst;
    if (i < n1)            d4[i] = ((const float4*)X1)[i];
    else if (i < 2 * n1)   d4[i] = ((const float4*)X2)[i - n1];
}

// ---------------------------------------------------------------------------
// transpose w_d (96,32,3,3) -> wT[g][c][k][o]  (o contiguous, 32-wide)
// ---------------------------------------------------------------------------
__global__ void transpose_wd(const float* __restrict__ w_d,
                             float* __restrict__ wT) {
    int i = blockIdx.x * 256 + threadIdx.x;       // 27648 total
    if (i >= 27648) return;
    int o = i & 31;
    int t = i >> 5;
    int k = t % 9; t /= 9;
    int c = t & 31;
    int g = t >> 5;
    wT[i] = w_d[((g * 32 + o) * 32 + c) * 9 + k];
}

// ---------------------------------------------------------------------------
// 3x3 conv, pad 1, no bias.  Block: 16x16 pixels x 12 out-channels.
// LDS-staged 4 input channels per iteration.
// ---------------------------------------------------------------------------
template<int CIN>
__global__ __launch_bounds__(256) void conv3x3_k(const float* __restrict__ in,
                                                 const float* __restrict__ w,
                                                 float* __restrict__ out,
                                                 int Cout) {
    __shared__ float s_in[4][18][18];   // [cin_sub][row][col], row/col include halo
    __shared__ float s_w[4][9][12];     // [cin_sub][tap][oc]

    const int tx = threadIdx.x, ty = threadIdx.y;
    const int tid = ty * 16 + tx;
    const int gx0 = blockIdx.x * 16, gy0 = blockIdx.y * 16;
    const int oc0 = blockIdx.z * 12;

    float acc[12];
#pragma unroll
    for (int j = 0; j < 12; ++j) acc[j] = 0.f;

    for (int cin0 = 0; cin0 < CIN; cin0 += 4) {
        __syncthreads();
        // stage input tiles (4 channels x 18x18)
        for (int i = tid; i < 4 * 324; i += 256) {
            int ch = i / 324;
            int rem = i - ch * 324;
            int r = rem / 18;
            int cc = rem - r * 18;
            int gy = gy0 + r - 1, gx = gx0 + cc - 1;
            float v = 0.f;
            if ((unsigned)gy < 128u && (unsigned)gx < 128u)
                v = in[(cin0 + ch) * HW + gy * W_ + gx];
            ((float*)s_in)[i] = v;
        }
        // stage weights (4 x 9 x 12 = 432 > 256 threads -> strided loop!)
        for (int i = tid; i < 432; i += 256) {
            int cb = i / 108;
            int rem = i - cb * 108;
            int tap = rem / 12;
            int oc = rem - tap * 12;
            int ocg = oc0 + oc;
            float v = (ocg < Cout) ? w[(ocg * CIN + cin0 + cb) * 9 + tap] : 0.f;
            s_w[cb][tap][oc] = v;
        }
        __syncthreads();

#pragma unroll
        for (int cb = 0; cb < 4; ++cb) {
#pragma unroll
            for (int tap = 0; tap < 9; ++tap) {
                float xv = s_in[cb][ty + tap / 3][tx + tap % 3];
                const float* wr = &s_w[cb][tap][0];
                float4 w0 = *(const float4*)wr;
                float4 w1 = *(const float4*)(wr + 4);
                float4 w2 = *(const float4*)(wr + 8);
                acc[0]  += xv * w0.x; acc[1]  += xv * w0.y;
                acc[2]  += xv * w0.z; acc[3]  += xv * w0.w;
                acc[4]  += xv * w1.x; acc[5]  += xv * w1.y;
                acc[6]  += xv * w1.z; acc[7]  += xv * w1.w;
                acc[8]  += xv * w2.x; acc[9]  += xv * w2.y;
                acc[10] += xv * w2.z; acc[11] += xv * w2.w;
            }
        }
    }

    const int px = gx0 + tx, py = gy0 + ty;
#pragma unroll
    for (int j = 0; j < 12; ++j) {
        int ocg = oc0 + j;
        if (ocg < Cout) out[ocg * HW + py * W_ + px] = acc[j];
    }
}

// ---------------------------------------------------------------------------
// Modulated deformable conv (DCNv2), groups=3, Cg=32, K=9.
// Block: 256 threads = 64 pixels x 4 c-subsets; blockIdx.y = group.
// wT (per group 32x9x32) staged in LDS; acc[32] out channels in registers;
// 4-lane shfl_xor reduction over the c-split.
// ---------------------------------------------------------------------------
__global__ __launch_bounds__(256) void dcn_kernel(const float* __restrict__ feat,
                                                  const float* __restrict__ off_raw,
                                                  const float* __restrict__ wT,
                                                  const float* __restrict__ b_d,
                                                  float* __restrict__ out) {
    __shared__ float s_w[9216];   // [c][k][o] for this group

    const int g = blockIdx.y;
    {
        const float4* src = (const float4*)(wT + g * 9216);
        float4* dst = (float4*)s_w;
        for (int i = threadIdx.x; i < 2304; i += 256) dst[i] = src[i];
    }
    __syncthreads();

    const int tid = threadIdx.x;
    const int csub = tid & 3;
    const int lp = tid >> 2;
    const int p = blockIdx.x * 64 + lp;
    const int y = p >> 7, x = p & 127;
    const float* fg = feat + g * 32 * HW;
    const int cbase = csub * 8;

    float acc[32];
#pragma unroll
    for (int o = 0; o < 32; ++o) acc[o] = 0.f;

#pragma unroll
    for (int k = 0; k < 9; ++k) {
        const int offch = g * 9 + k;
        float dyv = off_raw[offch * HW + p];
        float dxv = off_raw[(27 + offch) * HW + p];
        float mr  = off_raw[(54 + offch) * HW + p];
        float m = 1.f / (1.f + __expf(-mr));

        float py = dyv + (float)y + (float)(k / 3 - 1);
        float px = dxv + (float)x + (float)(k % 3 - 1);
        float y0f = floorf(py), x0f = floorf(px);
        float fy = py - y0f, fx = px - x0f;

        float vy0 = (y0f >= 0.f   && y0f <= 127.f) ? 1.f : 0.f;
        float vy1 = (y0f >= -1.f  && y0f <= 126.f) ? 1.f : 0.f;
        float vx0 = (x0f >= 0.f   && x0f <= 127.f) ? 1.f : 0.f;
        float vx1 = (x0f >= -1.f  && x0f <= 126.f) ? 1.f : 0.f;

        int iy0r = (int)y0f, ix0r = (int)x0f;
        int iy0 = min(max(iy0r, 0), 127);
        int iy1 = min(max(iy0r + 1, 0), 127);
        int ix0 = min(max(ix0r, 0), 127);
        int ix1 = min(max(ix0r + 1, 0), 127);

        float w00 = (1.f - fy) * (1.f - fx) * vy0 * vx0 * m;
        float w01 = (1.f - fy) * fx        * vy0 * vx1 * m;
        float w10 = fy        * (1.f - fx) * vy1 * vx0 * m;
        float w11 = fy        * fx         * vy1 * vx1 * m;

        int o00 = iy0 * W_ + ix0, o01 = iy0 * W_ + ix1;
        int o10 = iy1 * W_ + ix0, o11 = iy1 * W_ + ix1;

#pragma unroll
        for (int c8 = 0; c8 < 8; ++c8) {
            int c = cbase + c8;
            const float* fc = fg + c * HW;
            float v = w00 * fc[o00] + w01 * fc[o01] + w10 * fc[o10] + w11 * fc[o11];
            const float4* wv = (const float4*)&s_w[(c * 9 + k) * 32];
#pragma unroll
            for (int j = 0; j < 8; ++j) {
                float4 ww = wv[j];
                acc[4 * j + 0] += v * ww.x;
                acc[4 * j + 1] += v * ww.y;
                acc[4 * j + 2] += v * ww.z;
                acc[4 * j + 3] += v * ww.w;
            }
        }
    }

    // reduce the c-split across the 4 csub lanes (same pixel)
#pragma unroll
    for (int o = 0; o < 32; ++o) {
        acc[o] += __shfl_xor(acc[o], 1);
        acc[o] += __shfl_xor(acc[o], 2);
    }

    // each lane writes its 8 channels; static acc indices only (no scratch)
#pragma unroll
    for (int j = 0; j < 8; ++j) {
        float vj = (csub == 0) ? acc[j]
                 : (csub == 1) ? acc[8 + j]
                 : (csub == 2) ? acc[16 + j]
                 :               acc[24 + j];
        int ch = g * 32 + csub * 8 + j;
        out[ch * HW + p] = vj + b_d[ch];
    }
}

// ---------------------------------------------------------------------------
extern "C" void kernel_launch(void* const* d_in, const int* in_sizes, int n_in,
                              void* d_out, int out_size, void* d_ws, size_t ws_size,
                              hipStream_t stream) {
    const float* X1    = (const float*)d_in[0];
    const float* X2    = (const float*)d_in[1];
    const float* w_bot = (const float*)d_in[2];
    // dict order: w_off{i}, w_d{i}, b_d{i} interleaved
    const float* w_off[4] = {(const float*)d_in[3], (const float*)d_in[6],
                             (const float*)d_in[9], (const float*)d_in[12]};
    const float* w_d[4]   = {(const float*)d_in[4], (const float*)d_in[7],
                             (const float*)d_in[10], (const float*)d_in[13]};
    const float* b_d[4]   = {(const float*)d_in[5], (const float*)d_in[8],
                             (const float*)d_in[11], (const float*)d_in[14]};

    float* ws = (float*)d_ws;
    // overlay layout (floats):
    //   [0, 1572864)            featB            (overlaps bufin, which dies first)
    //   [1572864, 2899968)      off_raw (81*HW)
    //   [0, 3145728)            bufin (192*HW)   only live before first conv output
    //   [3145728, 4718592)      featA
    //   [4718592, +110592)      wT x4 layers
    float* featB   = ws;
    float* off_raw = ws + 1572864;
    float* bufin   = ws;
    float* featA   = ws + 3145728;
    float* wT      = ws + 4718592;

    pack_concat<<<3072, 256, 0, stream>>>(X1, X2, bufin);
    for (int l = 0; l < 4; ++l)
        transpose_wd<<<108, 256, 0, stream>>>(w_d[l], wT + l * 27648);

    conv3x3_k<192><<<dim3(8, 8, 8), dim3(16, 16), 0, stream>>>(bufin, w_bot, featA, 96);

    float* cur = featA;
    float* nxt = featB;
    for (int it = 0; it < 4; ++it) {
        conv3x3_k<96><<<dim3(8, 8, 7), dim3(16, 16), 0, stream>>>(cur, w_off[it], off_raw, 81);
        float* outp = (it == 3) ? (float*)d_out : nxt;
        dcn_kernel<<<dim3(256, 3), 256, 0, stream>>>(cur, off_raw, wT + it * 27648, b_d[it], outp);
        float* t = cur; cur = nxt; nxt = t;
    }
}

// Round 3
// 794.829 us; speedup vs baseline: 1.0132x; 1.0132x over previous
//
#include <hip/hip_runtime.h>
#include <hip/hip_bf16.h>

#define HW 16384   // 128*128
#define W_ 128

#define GSZ 9264   // padded per-group DCN weight slab (floats), 16B-aligned rows

// ---------------------------------------------------------------------------
// transpose conv weight w[oc][cin][3][3] -> wT[cin][tap][OCP], zero-pad oc>=Cout
// ---------------------------------------------------------------------------
__global__ void transpose_wc(const float* __restrict__ w, float* __restrict__ wT,
                             int CIN, int Cout, int OCP) {
    int i = blockIdx.x * 256 + threadIdx.x;
    int total = CIN * 9 * OCP;
    if (i >= total) return;
    int oc = i % OCP;
    int t = i / OCP;
    int tap = t % 9;
    int cin = t / 9;
    wT[i] = (oc < Cout) ? w[(oc * CIN + cin) * 9 + tap] : 0.f;
}

// ---------------------------------------------------------------------------
// transpose w_d (96,32,3,3) -> wT[g][(c*9+k)*32 + (c>>3)*4 + o]  (bank-staggered)
// ---------------------------------------------------------------------------
__global__ void transpose_wd(const float* __restrict__ w_d,
                             float* __restrict__ wT) {
    int i = blockIdx.x * 256 + threadIdx.x;       // 27648 total
    if (i >= 27648) return;
    int o = i & 31;
    int t = i >> 5;
    int k = t % 9; t /= 9;
    int c = t & 31;
    int g = t >> 5;
    wT[g * GSZ + ((c * 9 + k) << 5) + ((c >> 3) << 2) + o] =
        w_d[((g * 32 + o) * 32 + c) * 9 + k];
}

// ---------------------------------------------------------------------------
// Offset conv: 96 -> 81 channels, 3x3, pad 1.  One wave = 16x4 pixel tile,
// 12 output channels per block.  Weights via uniform (SGPR) loads from
// wT[cin][tap][84]; feature loads direct-global with imm offsets (input
// buffer has >=192-float slack on both sides; OOB lanes cndmask'd to 0).
// ---------------------------------------------------------------------------
__global__ __launch_bounds__(64) void conv_off_k(const float* __restrict__ in,
                                                 const float* __restrict__ wT,
                                                 float* __restrict__ out) {
    const int tx = threadIdx.x & 15;
    const int ty = threadIdx.x >> 4;
    const int px = (blockIdx.x << 4) + tx;
    const int py = (blockIdx.y << 2) + ty;
    const int oc0 = __builtin_amdgcn_readfirstlane(blockIdx.z * 12);

    bool vmask[9];
#pragma unroll
    for (int t = 0; t < 9; ++t) {
        int dy = t / 3 - 1, dx = t % 3 - 1;
        vmask[t] = ((unsigned)(py + dy) < 128u) & ((unsigned)(px + dx) < 128u);
    }

    const float* bc = in + py * W_ + px;
    const float* wr = wT + oc0;
    float acc[12];
#pragma unroll
    for (int j = 0; j < 12; ++j) acc[j] = 0.f;

#pragma unroll 2
    for (int cin = 0; cin < 96; ++cin) {
        float xv[9];
#pragma unroll
        for (int t = 0; t < 9; ++t) {
            int dy = t / 3 - 1, dx = t % 3 - 1;
            float ld = bc[dy * W_ + dx];      // imm offset, may touch pad region
            xv[t] = vmask[t] ? ld : 0.f;
        }
#pragma unroll
        for (int t = 0; t < 9; ++t) {
#pragma unroll
            for (int j = 0; j < 12; ++j)
                acc[j] += xv[t] * wr[t * 84 + j];   // uniform -> s_load
        }
        bc += HW;
        wr += 9 * 84;
    }

    const int p = py * W_ + px;
#pragma unroll
    for (int j = 0; j < 12; ++j) {
        int ocg = oc0 + j;
        if (ocg < 81) out[ocg * HW + p] = acc[j];
    }
}

// ---------------------------------------------------------------------------
// Bottom conv: cat(X1,X2) 192 -> 96 channels.  Reads X1/X2 directly with
// per-tap CLAMPED offsets (never OOB on harness inputs), invalid lanes
// masked to 0.  Weights wT[cin][tap][96] via SGPR loads.
// ---------------------------------------------------------------------------
__global__ __launch_bounds__(64) void conv_bot_k(const float* __restrict__ X1,
                                                 const float* __restrict__ X2,
                                                 const float* __restrict__ wT,
                                                 float* __restrict__ out) {
    const int tx = threadIdx.x & 15;
    const int ty = threadIdx.x >> 4;
    const int px = (blockIdx.x << 4) + tx;
    const int py = (blockIdx.y << 2) + ty;
    const int oc0 = __builtin_amdgcn_readfirstlane(blockIdx.z * 12);

    int toff[9];
    bool vmask[9];
#pragma unroll
    for (int t = 0; t < 9; ++t) {
        int dy = t / 3 - 1, dx = t % 3 - 1;
        int yy = min(max(py + dy, 0), 127);
        int xx = min(max(px + dx, 0), 127);
        toff[t] = yy * W_ + xx;
        vmask[t] = ((unsigned)(py + dy) < 128u) & ((unsigned)(px + dx) < 128u);
    }

    float acc[12];
#pragma unroll
    for (int j = 0; j < 12; ++j) acc[j] = 0.f;

    const float* wr = wT + oc0;
    const float* s = X1;
#pragma unroll 1
    for (int half = 0; half < 2; ++half) {
#pragma unroll 2
        for (int cin = 0; cin < 96; ++cin) {
            float xv[9];
#pragma unroll
            for (int t = 0; t < 9; ++t) {
                float ld = s[toff[t]];
                xv[t] = vmask[t] ? ld : 0.f;
            }
#pragma unroll
            for (int t = 0; t < 9; ++t) {
#pragma unroll
                for (int j = 0; j < 12; ++j)
                    acc[j] += xv[t] * wr[t * 96 + j];
            }
            s += HW;
            wr += 9 * 96;
        }
        s = X2;
    }

    const int p = py * W_ + px;
#pragma unroll
    for (int j = 0; j < 12; ++j)
        out[(oc0 + j) * HW + p] = acc[j];
}

// ---------------------------------------------------------------------------
// Modulated deformable conv (DCNv2), groups=3, Cg=32, K=9.
// Block: 256 threads = 64 pixels x 4 c-subsets; blockIdx.y = group.
// Bank-staggered wT slab in LDS; acc[32] out channels in registers;
// 4-lane shfl_xor reduction over the c-split.
// ---------------------------------------------------------------------------
__global__ __launch_bounds__(256) void dcn_kernel(const float* __restrict__ feat,
                                                  const float* __restrict__ off_raw,
                                                  const float* __restrict__ wT,
                                                  const float* __restrict__ b_d,
                                                  float* __restrict__ out) {
    __shared__ float s_w[GSZ];

    const int g = blockIdx.y;
    {
        const float4* src = (const float4*)(wT + g * GSZ);
        float4* dst = (float4*)s_w;
        for (int i = threadIdx.x; i < GSZ / 4; i += 256) dst[i] = src[i];
    }
    __syncthreads();

    const int tid = threadIdx.x;
    const int csub = tid & 3;
    const int lp = tid >> 2;
    const int p = blockIdx.x * 64 + lp;
    const int y = p >> 7, x = p & 127;
    const float* fg = feat + g * 32 * HW;
    const int cbase = csub * 8;

    float acc[32];
#pragma unroll
    for (int o = 0; o < 32; ++o) acc[o] = 0.f;

#pragma unroll
    for (int k = 0; k < 9; ++k) {
        const int offch = g * 9 + k;
        float dyv = off_raw[offch * HW + p];
        float dxv = off_raw[(27 + offch) * HW + p];
        float mr  = off_raw[(54 + offch) * HW + p];
        float m = 1.f / (1.f + __expf(-mr));

        float py = dyv + (float)y + (float)(k / 3 - 1);
        float px = dxv + (float)x + (float)(k % 3 - 1);
        float y0f = floorf(py), x0f = floorf(px);
        float fy = py - y0f, fx = px - x0f;

        float vy0 = (y0f >= 0.f   && y0f <= 127.f) ? 1.f : 0.f;
        float vy1 = (y0f >= -1.f  && y0f <= 126.f) ? 1.f : 0.f;
        float vx0 = (x0f >= 0.f   && x0f <= 127.f) ? 1.f : 0.f;
        float vx1 = (x0f >= -1.f  && x0f <= 126.f) ? 1.f : 0.f;

        int iy0r = (int)y0f, ix0r = (int)x0f;
        int iy0 = min(max(iy0r, 0), 127);
        int iy1 = min(max(iy0r + 1, 0), 127);
        int ix0 = min(max(ix0r, 0), 127);
        int ix1 = min(max(ix0r + 1, 0), 127);

        float w00 = (1.f - fy) * (1.f - fx) * vy0 * vx0 * m;
        float w01 = (1.f - fy) * fx        * vy0 * vx1 * m;
        float w10 = fy        * (1.f - fx) * vy1 * vx0 * m;
        float w11 = fy        * fx         * vy1 * vx1 * m;

        int o00 = iy0 * W_ + ix0, o01 = iy0 * W_ + ix1;
        int o10 = iy1 * W_ + ix0, o11 = iy1 * W_ + ix1;

#pragma unroll
        for (int c8 = 0; c8 < 8; ++c8) {
            int c = cbase + c8;
            const float* fc = fg + c * HW;
            float v = w00 * fc[o00] + w01 * fc[o01] + w10 * fc[o10] + w11 * fc[o11];
            const float4* wv = (const float4*)&s_w[((c * 9 + k) << 5) + ((c >> 3) << 2)];
#pragma unroll
            for (int j = 0; j < 8; ++j) {
                float4 ww = wv[j];
                acc[4 * j + 0] += v * ww.x;
                acc[4 * j + 1] += v * ww.y;
                acc[4 * j + 2] += v * ww.z;
                acc[4 * j + 3] += v * ww.w;
            }
        }
    }

#pragma unroll
    for (int o = 0; o < 32; ++o) {
        acc[o] += __shfl_xor(acc[o], 1);
        acc[o] += __shfl_xor(acc[o], 2);
    }

#pragma unroll
    for (int j = 0; j < 8; ++j) {
        float vj = (csub == 0) ? acc[j]
                 : (csub == 1) ? acc[8 + j]
                 : (csub == 2) ? acc[16 + j]
                 :               acc[24 + j];
        int ch = g * 32 + csub * 8 + j;
        out[ch * HW + p] = vj + b_d[ch];
    }
}

// ---------------------------------------------------------------------------
extern "C" void kernel_launch(void* const* d_in, const int* in_sizes, int n_in,
                              void* d_out, int out_size, void* d_ws, size_t ws_size,
                              hipStream_t stream) {
    const float* X1    = (const float*)d_in[0];
    const float* X2    = (const float*)d_in[1];
    const float* w_bot = (const float*)d_in[2];
    const float* w_off[4] = {(const float*)d_in[3], (const float*)d_in[6],
                             (const float*)d_in[9], (const float*)d_in[12]};
    const float* w_d[4]   = {(const float*)d_in[4], (const float*)d_in[7],
                             (const float*)d_in[10], (const float*)d_in[13]};
    const float* b_d[4]   = {(const float*)d_in[5], (const float*)d_in[8],
                             (const float*)d_in[11], (const float*)d_in[14]};

    float* ws = (float*)d_ws;
    // layout (floats), 192-float pads around feat buffers for conv slack reads:
    const int PAD = 192;
    const int FREG = PAD + 96 * HW + PAD;        // 1,573,248
    float* featA   = ws + PAD;                   // region [0, FREG)
    float* featB   = ws + FREG + PAD;            // region [FREG, 2*FREG)
    float* off_raw = ws + 2 * FREG;              // 81*HW = 1,327,104
    float* wTc_bot = ws + 2 * FREG + 81 * HW;    // 192*9*96 = 165,888
    float* wTc_off = wTc_bot + 192 * 9 * 96;     // 96*9*84  = 72,576
    float* wTd     = wTc_off + 96 * 9 * 84;      // 3*GSZ    = 27,792
    // total ~4.74M floats = 19.0 MB

    transpose_wc<<<(192 * 9 * 96 + 255) / 256, 256, 0, stream>>>(w_bot, wTc_bot, 192, 96, 96);
    conv_bot_k<<<dim3(8, 32, 8), 64, 0, stream>>>(X1, X2, wTc_bot, featA);

    float* cur = featA;
    float* nxt = featB;
    for (int it = 0; it < 4; ++it) {
        transpose_wc<<<(96 * 9 * 84 + 255) / 256, 256, 0, stream>>>(w_off[it], wTc_off, 96, 81, 84);
        conv_off_k<<<dim3(8, 32, 7), 64, 0, stream>>>(cur, wTc_off, off_raw);
        transpose_wd<<<108, 256, 0, stream>>>(w_d[it], wTd);
        float* outp = (it == 3) ? (float*)d_out : nxt;
        dcn_kernel<<<dim3(256, 3), 256, 0, stream>>>(cur, off_raw, wTd, b_d[it], outp);
        float* t = cur; cur = nxt; nxt = t;
    }
}

// Round 5
// 670.946 us; speedup vs baseline: 1.2003x; 1.1846x over previous
//
#include <hip/hip_runtime.h>
#include <hip/hip_bf16.h>

#define HW 16384   // 128*128
#define W_ 128

#define GSZ 9264   // padded per-group DCN weight slab (floats), 16B-aligned rows

// ---------------------------------------------------------------------------
// transpose conv weight w[oc][cin][3][3] -> wT[cin][tap][OCP], zero-pad oc>=Cout
// ---------------------------------------------------------------------------
__global__ void transpose_wc(const float* __restrict__ w, float* __restrict__ wT,
                             int CIN, int Cout, int OCP) {
    int i = blockIdx.x * 256 + threadIdx.x;
    int total = CIN * 9 * OCP;
    if (i >= total) return;
    int oc = i % OCP;
    int t = i / OCP;
    int tap = t % 9;
    int cin = t / 9;
    wT[i] = (oc < Cout) ? w[(oc * CIN + cin) * 9 + tap] : 0.f;
}

// ---------------------------------------------------------------------------
// transpose w_d (96,32,3,3) -> wT[g][(c*9+k)*32 + (c>>3)*4 + o]  (bank-staggered)
// ---------------------------------------------------------------------------
__global__ void transpose_wd(const float* __restrict__ w_d,
                             float* __restrict__ wT) {
    int i = blockIdx.x * 256 + threadIdx.x;       // 27648 total
    if (i >= 27648) return;
    int o = i & 31;
    int t = i >> 5;
    int k = t % 9; t /= 9;
    int c = t & 31;
    int g = t >> 5;
    wT[g * GSZ + ((c * 9 + k) << 5) + ((c >> 3) << 2) + o] =
        w_d[((g * 32 + o) * 32 + c) * 9 + k];
}

// ---------------------------------------------------------------------------
// Offset conv: 96 -> 81 ch, 3x3 pad 1.  Wave = 16x4 pixels, 6 oc/thread.
// Grid 8x32x14 = 3584 waves (4/SIMD).  2-stage cin pipeline: prefetch next
// channel's 9 taps while FMA-ing current.  `in` is a ws buffer with 192-float
// pads, so imm-offset reads (incl. plane-96 prefetch overrun) stay in ws.
// ---------------------------------------------------------------------------
__global__ __launch_bounds__(64) void conv_off_k(const float* __restrict__ in,
                                                 const float* __restrict__ wT,
                                                 float* __restrict__ out) {
    const int tx = threadIdx.x & 15;
    const int ty = threadIdx.x >> 4;
    const int px = (blockIdx.x << 4) + tx;
    const int py = (blockIdx.y << 2) + ty;
    const int oc0 = __builtin_amdgcn_readfirstlane(blockIdx.z * 6);

    bool vm[9];
#pragma unroll
    for (int t = 0; t < 9; ++t) {
        int dy = t / 3 - 1, dx = t % 3 - 1;
        vm[t] = ((unsigned)(py + dy) < 128u) & ((unsigned)(px + dx) < 128u);
    }

    const float* bc = in + py * W_ + px;
    const float* wr = wT + oc0;
    float acc[6];
#pragma unroll
    for (int j = 0; j < 6; ++j) acc[j] = 0.f;

    float xv[9];
#pragma unroll
    for (int t = 0; t < 9; ++t) {
        int dy = t / 3 - 1, dx = t % 3 - 1;
        float ld = bc[dy * W_ + dx];
        xv[t] = vm[t] ? ld : 0.f;
    }

#pragma unroll 2
    for (int cin = 0; cin < 96; ++cin) {
        const float* nb = bc + HW;
        float nx[9];
#pragma unroll
        for (int t = 0; t < 9; ++t) {
            int dy = t / 3 - 1, dx = t % 3 - 1;
            float ld = nb[dy * W_ + dx];          // overrun stays inside ws
            nx[t] = vm[t] ? ld : 0.f;
        }
#pragma unroll
        for (int t = 0; t < 9; ++t) {
#pragma unroll
            for (int j = 0; j < 6; ++j)
                acc[j] += xv[t] * wr[t * 84 + j];  // uniform -> scalar loads
        }
#pragma unroll
        for (int t = 0; t < 9; ++t) xv[t] = nx[t];
        bc = nb;
        wr += 9 * 84;
    }

    const int p = py * W_ + px;
#pragma unroll
    for (int j = 0; j < 6; ++j) {
        int ocg = oc0 + j;
        if (ocg < 81) out[ocg * HW + p] = acc[j];
    }
}

// ---------------------------------------------------------------------------
// Bottom conv: cat(X1,X2) 192 -> 96 ch.  Reads harness inputs X1/X2, so all
// taps use CLAMPED in-plane offsets (never OOB); invalid lanes masked to 0.
// 2-stage cin pipeline over plane pointers; last prefetch clamps to plane 191.
// Grid 8x32x16 = 4096 waves.
// ---------------------------------------------------------------------------
__global__ __launch_bounds__(64) void conv_bot_k(const float* __restrict__ X1,
                                                 const float* __restrict__ X2,
                                                 const float* __restrict__ wT,
                                                 float* __restrict__ out) {
    const int tx = threadIdx.x & 15;
    const int ty = threadIdx.x >> 4;
    const int px = (blockIdx.x << 4) + tx;
    const int py = (blockIdx.y << 2) + ty;
    const int oc0 = __builtin_amdgcn_readfirstlane(blockIdx.z * 6);

    int toff[9];
    bool vm[9];
#pragma unroll
    for (int t = 0; t < 9; ++t) {
        int dy = t / 3 - 1, dx = t % 3 - 1;
        int yy = min(max(py + dy, 0), 127);
        int xx = min(max(px + dx, 0), 127);
        toff[t] = yy * W_ + xx;                 // always inside a plane
        vm[t] = ((unsigned)(py + dy) < 128u) & ((unsigned)(px + dx) < 128u);
    }

    const float* wr = wT + oc0;
    float acc[6];
#pragma unroll
    for (int j = 0; j < 6; ++j) acc[j] = 0.f;

    float xv[9];
    {
        const float* pb = X1;                   // plane 0
#pragma unroll
        for (int t = 0; t < 9; ++t) {
            float ld = pb[toff[t]];
            xv[t] = vm[t] ? ld : 0.f;
        }
    }

#pragma unroll 2
    for (int cin = 0; cin < 192; ++cin) {
        int nc = min(cin + 1, 191);             // clamp final prefetch plane
        const float* nb = (nc < 96) ? X1 + nc * HW : X2 + (nc - 96) * HW;
        float nx[9];
#pragma unroll
        for (int t = 0; t < 9; ++t) {
            float ld = nb[toff[t]];
            nx[t] = vm[t] ? ld : 0.f;
        }
#pragma unroll
        for (int t = 0; t < 9; ++t) {
#pragma unroll
            for (int j = 0; j < 6; ++j)
                acc[j] += xv[t] * wr[t * 96 + j];
        }
#pragma unroll
        for (int t = 0; t < 9; ++t) xv[t] = nx[t];
        wr += 9 * 96;
    }

    const int p = py * W_ + px;
#pragma unroll
    for (int j = 0; j < 6; ++j)
        out[(oc0 + j) * HW + p] = acc[j];
}

// ---------------------------------------------------------------------------
// Modulated deformable conv (DCNv2), groups=3, Cg=32, K=9.
// Block: 256 threads = 64 pixels x 4 c-subsets; blockIdx.y = group.
// All 27 offset/mask loads issued up-front for latency overlap.
// ---------------------------------------------------------------------------
__global__ __launch_bounds__(256) void dcn_kernel(const float* __restrict__ feat,
                                                  const float* __restrict__ off_raw,
                                                  const float* __restrict__ wT,
                                                  const float* __restrict__ b_d,
                                                  float* __restrict__ out) {
    __shared__ float s_w[GSZ];

    const int g = blockIdx.y;
    {
        const float4* src = (const float4*)(wT + g * GSZ);
        float4* dst = (float4*)s_w;
        for (int i = threadIdx.x; i < GSZ / 4; i += 256) dst[i] = src[i];
    }
    __syncthreads();

    const int tid = threadIdx.x;
    const int csub = tid & 3;
    const int lp = tid >> 2;
    const int p = blockIdx.x * 64 + lp;
    const int y = p >> 7, x = p & 127;
    const float* fg = feat + g * 32 * HW;
    const int cbase = csub * 8;

    // preload all offsets/masks (27 outstanding loads)
    float dyv[9], dxv[9], mrv[9];
#pragma unroll
    for (int k = 0; k < 9; ++k) {
        const int offch = g * 9 + k;
        dyv[k] = off_raw[offch * HW + p];
        dxv[k] = off_raw[(27 + offch) * HW + p];
        mrv[k] = off_raw[(54 + offch) * HW + p];
    }

    float acc[32];
#pragma unroll
    for (int o = 0; o < 32; ++o) acc[o] = 0.f;

#pragma unroll
    for (int k = 0; k < 9; ++k) {
        float m = 1.f / (1.f + __expf(-mrv[k]));

        float py = dyv[k] + (float)y + (float)(k / 3 - 1);
        float px = dxv[k] + (float)x + (float)(k % 3 - 1);
        float y0f = floorf(py), x0f = floorf(px);
        float fy = py - y0f, fx = px - x0f;

        float vy0 = (y0f >= 0.f   && y0f <= 127.f) ? 1.f : 0.f;
        float vy1 = (y0f >= -1.f  && y0f <= 126.f) ? 1.f : 0.f;
        float vx0 = (x0f >= 0.f   && x0f <= 127.f) ? 1.f : 0.f;
        float vx1 = (x0f >= -1.f  && x0f <= 126.f) ? 1.f : 0.f;

        int iy0r = (int)y0f, ix0r = (int)x0f;
        int iy0 = min(max(iy0r, 0), 127);
        int iy1 = min(max(iy0r + 1, 0), 127);
        int ix0 = min(max(ix0r, 0), 127);
        int ix1 = min(max(ix0r + 1, 0), 127);

        float w00 = (1.f - fy) * (1.f - fx) * vy0 * vx0 * m;
        float w01 = (1.f - fy) * fx        * vy0 * vx1 * m;
        float w10 = fy        * (1.f - fx) * vy1 * vx0 * m;
        float w11 = fy        * fx         * vy1 * vx1 * m;

        int o00 = iy0 * W_ + ix0, o01 = iy0 * W_ + ix1;
        int o10 = iy1 * W_ + ix0, o11 = iy1 * W_ + ix1;

#pragma unroll
        for (int c8 = 0; c8 < 8; ++c8) {
            int c = cbase + c8;
            const float* fc = fg + c * HW;
            float v = w00 * fc[o00] + w01 * fc[o01] + w10 * fc[o10] + w11 * fc[o11];
            const float4* wv = (const float4*)&s_w[((c * 9 + k) << 5) + ((c >> 3) << 2)];
#pragma unroll
            for (int j = 0; j < 8; ++j) {
                float4 ww = wv[j];
                acc[4 * j + 0] += v * ww.x;
                acc[4 * j + 1] += v * ww.y;
                acc[4 * j + 2] += v * ww.z;
                acc[4 * j + 3] += v * ww.w;
            }
        }
    }

#pragma unroll
    for (int o = 0; o < 32; ++o) {
        acc[o] += __shfl_xor(acc[o], 1);
        acc[o] += __shfl_xor(acc[o], 2);
    }

#pragma unroll
    for (int j = 0; j < 8; ++j) {
        float vj = (csub == 0) ? acc[j]
                 : (csub == 1) ? acc[8 + j]
                 : (csub == 2) ? acc[16 + j]
                 :               acc[24 + j];
        int ch = g * 32 + csub * 8 + j;
        out[ch * HW + p] = vj + b_d[ch];
    }
}

// ---------------------------------------------------------------------------
extern "C" void kernel_launch(void* const* d_in, const int* in_sizes, int n_in,
                              void* d_out, int out_size, void* d_ws, size_t ws_size,
                              hipStream_t stream) {
    const float* X1    = (const float*)d_in[0];
    const float* X2    = (const float*)d_in[1];
    const float* w_bot = (const float*)d_in[2];
    const float* w_off[4] = {(const float*)d_in[3], (const float*)d_in[6],
                             (const float*)d_in[9], (const float*)d_in[12]};
    const float* w_d[4]   = {(const float*)d_in[4], (const float*)d_in[7],
                             (const float*)d_in[10], (const float*)d_in[13]};
    const float* b_d[4]   = {(const float*)d_in[5], (const float*)d_in[8],
                             (const float*)d_in[11], (const float*)d_in[14]};

    float* ws = (float*)d_ws;
    // layout (floats), 192-float pads; conv_off prefetch overruns land in the
    // next ws region, which is always valid memory:
    const int PAD = 192;
    const int FREG = PAD + 96 * HW + PAD;        // 1,573,248
    float* featA   = ws + PAD;                   // region [0, FREG)
    float* featB   = ws + FREG + PAD;            // region [FREG, 2*FREG)
    float* off_raw = ws + 2 * FREG;              // 81*HW = 1,327,104
    float* wTc_bot = ws + 2 * FREG + 81 * HW;    // 192*9*96 = 165,888
    float* wTc_off = wTc_bot + 192 * 9 * 96;     // 96*9*84  = 72,576
    float* wTd     = wTc_off + 96 * 9 * 84;      // 3*GSZ    = 27,792
    // total ~4.74M floats = 19.0 MB

    transpose_wc<<<(192 * 9 * 96 + 255) / 256, 256, 0, stream>>>(w_bot, wTc_bot, 192, 96, 96);
    conv_bot_k<<<dim3(8, 32, 16), 64, 0, stream>>>(X1, X2, wTc_bot, featA);

    float* cur = featA;
    float* nxt = featB;
    for (int it = 0; it < 4; ++it) {
        transpose_wc<<<(96 * 9 * 84 + 255) / 256, 256, 0, stream>>>(w_off[it], wTc_off, 96, 81, 84);
        conv_off_k<<<dim3(8, 32, 14), 64, 0, stream>>>(cur, wTc_off, off_raw);
        transpose_wd<<<108, 256, 0, stream>>>(w_d[it], wTd);
        float* outp = (it == 3) ? (float*)d_out : nxt;
        dcn_kernel<<<dim3(256, 3), 256, 0, stream>>>(cur, off_raw, wTd, b_d[it], outp);
        float* t = cur; cur = nxt; nxt = t;
    }
}